// Round 9
// baseline (528.884 us; speedup 1.0000x reference)
//
#include <hip/hip_runtime.h>

typedef __bf16 bfrag __attribute__((ext_vector_type(8)));
typedef float f32x4 __attribute__((ext_vector_type(4)));
typedef unsigned short us8 __attribute__((ext_vector_type(8)));

__device__ __forceinline__ float bf2f(unsigned short s) {
  unsigned u = ((unsigned)s) << 16;
  float f;
  __builtin_memcpy(&f, &u, 4);
  return f;
}
__device__ __forceinline__ unsigned short f2bf(float f) {
  unsigned u;
  __builtin_memcpy(&u, &f, 4);
  u += 0x7fffu + ((u >> 16) & 1u);
  return (unsigned short)(u >> 16);
}
__device__ __forceinline__ float rdf(const void* p, size_t i, int isf) {
  return isf ? ((const float*)p)[i] : bf2f(((const unsigned short*)p)[i]);
}
__device__ __forceinline__ void gld16(const unsigned short* g, unsigned short* l) {
  __builtin_amdgcn_global_load_lds(
      (const __attribute__((address_space(1))) unsigned int*)g,
      (__attribute__((address_space(3))) unsigned int*)l, 16, 0, 0);
}

struct MArgs {
  const unsigned short* x16;
  const int* mask;
  const void *wq, *wk, *wv, *wo, *w1, *w2;
  const void *bq, *bk, *bv, *bo, *b1, *b2;
  const void *alpha1, *beta1, *alpha2, *beta2;
  void* d_out;
  unsigned* bar;          // spin-barrier arrival counter (zeroed pre-launch)
  unsigned* gen;          // spin-barrier generation     (zeroed pre-launch)
  unsigned short* wqkvT;  // [1536][512]
  unsigned short* woT;    // [512][512]
  unsigned short* w1T;    // [2048][512]
  unsigned short* w2T;    // [512][2048]
  float* bcat;            // 4608 f32
  float* x1;              // [8192][512] f32
  unsigned short* n1;     // [8192][512] (also ctx, n2)
  unsigned short* qkb;    // [8192][1536] (ff1 overlay)
  unsigned short* vbt;    // [2048][2048]
};

// -------- device-scope grid barrier (all 512 blocks co-resident) -------
__device__ __forceinline__ void gbar(unsigned* bar, unsigned* gen, unsigned nb) {
  __syncthreads();
  if (threadIdx.x == 0) {
    __threadfence();  // publish this block's phase writes
    unsigned g = __hip_atomic_load(gen, __ATOMIC_RELAXED, __HIP_MEMORY_SCOPE_AGENT);
    if (atomicAdd(bar, 1u) == nb - 1u) {
      __hip_atomic_store(bar, 0u, __ATOMIC_RELAXED, __HIP_MEMORY_SCOPE_AGENT);
      __threadfence();
      atomicAdd(gen, 1u);  // release
    } else {
      while (__hip_atomic_load(gen, __ATOMIC_RELAXED, __HIP_MEMORY_SCOPE_AGENT) == g)
        __builtin_amdgcn_s_sleep(8);
      __threadfence();  // acquire
    }
  }
  __syncthreads();
}

// -------- 32x32 transpose unit (bf16 out) ------------------------------
__device__ void trans_unit(const void* W, unsigned short* Wt, int K, int N,
                           int t, int isf, char* SM) {
  auto tile = (unsigned short(*)[33])SM;
  int tid = threadIdx.x;
  int nx = N >> 5;
  int n0 = (t % nx) * 32, k0 = (t / nx) * 32;
  __syncthreads();  // WAR vs previous unit's reads
#pragma unroll
  for (int i = 0; i < 4; i++) {
    int e = tid + i * 256;
    int r = e >> 5, c = e & 31;
    tile[r][c] = f2bf(rdf(W, (size_t)(k0 + r) * N + n0 + c, isf));
  }
  __syncthreads();
#pragma unroll
  for (int i = 0; i < 4; i++) {
    int e = tid + i * 256;
    int r = e >> 5, c = e & 31;
    Wt[(size_t)(n0 + r) * K + k0 + c] = tile[c][r];
  }
}

// -------- V transpose unit: qkb v-cols -> vbt[bh][d][s] ----------------
__device__ void vtrans_unit(const unsigned short* qkb, unsigned short* vbt,
                            int u, char* SM) {
  auto tile = (unsigned short(*)[33])SM;
  int tid = threadIdx.x;
  int s0 = (u & 63) * 32;
  int d0 = ((u >> 6) & 1) * 32;
  int bh = u >> 7, b = bh >> 3, h = bh & 7;
  __syncthreads();
#pragma unroll
  for (int i = 0; i < 4; i++) {
    int e = tid + i * 256;
    int r = e >> 5, c = e & 31;
    tile[r][c] = qkb[((size_t)b * 2048 + s0 + r) * 1536 + 1024 + h * 64 + d0 + c];
  }
  __syncthreads();
#pragma unroll
  for (int i = 0; i < 4; i++) {
    int e = tid + i * 256;
    int r = e >> 5, c = e & 31;
    vbt[((size_t)bh * 64 + d0 + r) * 2048 + s0 + c] = tile[c][r];
  }
}

// -------- layernorm unit: 4 tokens (1/wave) ----------------------------
template <int XMODE>
__device__ void norm_unit(const void* xin, const void* alpha, const void* beta,
                          unsigned short* out, int isf, int u) {
  constexpr int E = 512;
  int xf = XMODE ? 1 : isf;
  int tid = threadIdx.x;
  int wave = tid >> 6, lane = tid & 63;
  size_t tok = (size_t)u * 4 + wave;
  float v[8];
  if (xf) {
    const float* xp = (const float*)xin + tok * E + lane * 8;
    float4 a0 = *(const float4*)xp;
    float4 a1 = *(const float4*)(xp + 4);
    v[0] = a0.x; v[1] = a0.y; v[2] = a0.z; v[3] = a0.w;
    v[4] = a1.x; v[5] = a1.y; v[6] = a1.z; v[7] = a1.w;
  } else {
    us8 uu = *(const us8*)((const unsigned short*)xin + tok * E + lane * 8);
#pragma unroll
    for (int j = 0; j < 8; j++) v[j] = bf2f(uu[j]);
  }
  float s = 0.f, sq = 0.f;
#pragma unroll
  for (int j = 0; j < 8; j++) { s += v[j]; sq += v[j] * v[j]; }
#pragma unroll
  for (int off = 1; off < 64; off <<= 1) {
    s += __shfl_xor(s, off, 64);
    sq += __shfl_xor(sq, off, 64);
  }
  float mean = s * (1.0f / 512.0f);
  float var = fmaxf((sq - 512.0f * mean * mean) * (1.0f / 511.0f), 0.0f);
  float inv = rdf(alpha, 0, isf) / (sqrtf(var) + 1e-6f);
  float be = rdf(beta, 0, isf);
  us8 ov;
#pragma unroll
  for (int j = 0; j < 8; j++) ov[j] = f2bf((v[j] - mean) * inv + be);
  *(us8*)(out + tok * E + lane * 8) = ov;
}

// -------- GEMM tile (m97-style, BK=32, global_load_lds) ----------------
// SM: As[128*32] at 0, Bs[TN*32] at 8192.
template <int TN, int RES, int OUTM, int RELU>
__device__ void gemm_tile(const unsigned short* __restrict__ A,
                          const unsigned short* __restrict__ Bt,
                          const float* __restrict__ bias,
                          const void* __restrict__ res, void* __restrict__ outp,
                          int N, int K, int isf, int mi, int ni, char* SM) {
  constexpr int MT = (TN == 128) ? 4 : 2;
  unsigned short* As = (unsigned short*)SM;
  unsigned short* Bs = (unsigned short*)(SM + 8192);
  int outf32 = (OUTM == 1) || (OUTM == 2 && isf);
  int tid = threadIdx.x;
  int wave = tid >> 6, lane = tid & 63;
  int quad = lane >> 4, l16 = lane & 15;
  int wm = (TN == 128) ? (wave >> 1) : wave;
  int wn = (TN == 128) ? (wave & 1) : 0;
  size_t m0 = (size_t)mi * 128;
  size_t n0 = (size_t)ni * TN;

  int lrow = lane >> 2;
  int kseg = (lane & 3) * 8;

  const unsigned short* ag = A + (m0 + wave * 16 + lrow) * K + kseg;
  const unsigned short* bg = Bt + (n0 + wave * 16 + lrow) * K + kseg;
  unsigned short* asl = &As[(wave * 16) * 32];
  unsigned short* bsl = &Bs[(wave * 16) * 32];

  f32x4 acc[MT][4];
#pragma unroll
  for (int i = 0; i < MT; i++)
#pragma unroll
    for (int j = 0; j < 4; j++) acc[i][j] = {0.f, 0.f, 0.f, 0.f};

  for (int k0 = 0; k0 < K; k0 += 32) {
    __syncthreads();
    gld16(ag + k0, asl);
    gld16(ag + (size_t)64 * K + k0, asl + 64 * 32);
    gld16(bg + k0, bsl);
    if (TN == 128) gld16(bg + (size_t)64 * K + k0, bsl + 64 * 32);
    __syncthreads();
    bfrag af[MT], bf[4];
#pragma unroll
    for (int i = 0; i < MT; i++)
      af[i] = *(const bfrag*)&As[(wm * (MT * 16) + i * 16 + l16) * 32 + quad * 8];
#pragma unroll
    for (int j = 0; j < 4; j++)
      bf[j] = *(const bfrag*)&Bs[(wn * 64 + j * 16 + l16) * 32 + quad * 8];
#pragma unroll
    for (int i = 0; i < MT; i++)
#pragma unroll
      for (int j = 0; j < 4; j++)
        acc[i][j] = __builtin_amdgcn_mfma_f32_16x16x32_bf16(af[i], bf[j], acc[i][j], 0, 0, 0);
  }
#pragma unroll
  for (int j = 0; j < 4; j++) {
    size_t n = n0 + wn * 64 + j * 16 + l16;
    float bv = bias[n];
#pragma unroll
    for (int i = 0; i < MT; i++) {
#pragma unroll
      for (int r = 0; r < 4; r++) {
        size_t m = m0 + wm * (MT * 16) + i * 16 + quad * 4 + r;
        float vv = acc[i][j][r] + bv;
        if (RELU) vv = fmaxf(vv, 0.0f);
        if (RES == 1) vv += rdf(res, m * N + n, isf);
        else if (RES == 2) vv += ((const float*)res)[m * N + n];
        if (outf32) ((float*)outp)[m * N + n] = vv;
        else ((unsigned short*)outp)[m * N + n] = f2bf(vv);
      }
    }
  }
}

// -------- attention tile (r6-proven): one (b,h) x 64 queries -----------
// SM: Kt[64][72] at 0, Vt[64][72] at 9216, Pl[4][16][68] at 18432, mskf at 27136
__device__ void attn_tile(const unsigned short* __restrict__ qkb,
                          const unsigned short* __restrict__ vbt,
                          const int* __restrict__ mask,
                          unsigned short* __restrict__ ctx,
                          int q0, int bh, char* SM) {
  constexpr int S = 2048;
  auto Kt = (unsigned short(*)[72])(SM);
  auto Vt = (unsigned short(*)[72])(SM + 9216);
  float* mskf = (float*)(SM + 27136);
  int tid = threadIdx.x, wave = tid >> 6, lane = tid & 63;
  int quad = lane >> 4, l16 = lane & 15;
  unsigned short* PlW = (unsigned short*)(SM + 18432) + wave * 16 * 68;
  int b = bh >> 3, h = bh & 7;
  size_t rowbase = (size_t)b * S;

  bfrag qf0, qf1;
  {
    const unsigned short* qp =
        qkb + (rowbase + q0 + wave * 16 + l16) * 1536 + h * 64 + quad * 8;
    qf0 = *(const bfrag*)qp;
    qf1 = *(const bfrag*)(qp + 32);
  }
  f32x4 o[4] = {{0, 0, 0, 0}, {0, 0, 0, 0}, {0, 0, 0, 0}, {0, 0, 0, 0}};
  float l_i[4] = {0.f, 0.f, 0.f, 0.f};

  int srow = tid >> 2;
  int c0 = (tid & 3) * 8;
  const unsigned short* kbase = qkb + 512 + h * 64;
  const unsigned short* vrow = vbt + ((size_t)bh * 64 + srow) * S;
  const float SC = 0.18033688f;  // 0.125 * log2(e)

  for (int kt = 0; kt < S; kt += 64) {
    __syncthreads();
    {
      const unsigned short* kp = kbase + (rowbase + kt + srow) * 1536;
      *(uint4*)&Kt[srow][c0]      = *(const uint4*)(kp + c0);
      *(uint4*)&Kt[srow][c0 + 32] = *(const uint4*)(kp + c0 + 32);
      *(uint4*)&Vt[srow][c0]      = *(const uint4*)(vrow + kt + c0);
      *(uint4*)&Vt[srow][c0 + 32] = *(const uint4*)(vrow + kt + c0 + 32);
    }
    if (tid < 64) mskf[tid] = mask[rowbase + kt + tid] ? 0.0f : -1e5f;
    __syncthreads();

    float pr[4][4];
#pragma unroll
    for (int nt = 0; nt < 4; nt++) {
      f32x4 s = {0, 0, 0, 0};
      bfrag k0f = *(const bfrag*)&Kt[nt * 16 + l16][quad * 8];
      bfrag k1f = *(const bfrag*)&Kt[nt * 16 + l16][32 + quad * 8];
      s = __builtin_amdgcn_mfma_f32_16x16x32_bf16(qf0, k0f, s, 0, 0, 0);
      s = __builtin_amdgcn_mfma_f32_16x16x32_bf16(qf1, k1f, s, 0, 0, 0);
      float mb = mskf[nt * 16 + l16];
#pragma unroll
      for (int r = 0; r < 4; r++) {
        float p = __builtin_amdgcn_exp2f(fminf(fmaf(s[r], SC, mb), 50.0f));
        pr[nt][r] = p;
        unsigned u;
        __builtin_memcpy(&u, &p, 4);
        PlW[(quad * 4 + r) * 68 + nt * 16 + l16] = (unsigned short)(u >> 16);
      }
    }
#pragma unroll
    for (int r = 0; r < 4; r++)
      l_i[r] += (pr[0][r] + pr[1][r]) + (pr[2][r] + pr[3][r]);
    // PlW wave-private; per-wave DS ordering -> no barrier
    bfrag pa0 = *(const bfrag*)&PlW[l16 * 68 + quad * 8];
    bfrag pa1 = *(const bfrag*)&PlW[l16 * 68 + 32 + quad * 8];
#pragma unroll
    for (int dt = 0; dt < 4; dt++) {
      bfrag v0 = *(const bfrag*)&Vt[dt * 16 + l16][quad * 8];
      bfrag v1 = *(const bfrag*)&Vt[dt * 16 + l16][32 + quad * 8];
      o[dt] = __builtin_amdgcn_mfma_f32_16x16x32_bf16(pa0, v0, o[dt], 0, 0, 0);
      o[dt] = __builtin_amdgcn_mfma_f32_16x16x32_bf16(pa1, v1, o[dt], 0, 0, 0);
    }
  }
#pragma unroll
  for (int r = 0; r < 4; r++) {
#pragma unroll
    for (int off = 1; off < 16; off <<= 1) l_i[r] += __shfl_xor(l_i[r], off, 64);
    l_i[r] = 1.0f / fmaxf(l_i[r], 1e-30f);
  }
#pragma unroll
  for (int dt = 0; dt < 4; dt++) {
#pragma unroll
    for (int r = 0; r < 4; r++) {
      size_t qrow = rowbase + q0 + wave * 16 + quad * 4 + r;
      ctx[qrow * 512 + h * 64 + dt * 16 + l16] = f2bf(o[dt][r] * l_i[r]);
    }
  }
}

// -------- persistent mega-kernel: 8 phases, 7 spin barriers ------------
// grid=512, __launch_bounds__(256,2): every resource <= half a CU ->
// all 512 blocks provably co-resident (2/CU); spin barrier is safe.
__global__ __launch_bounds__(256, 2) void mega_k(MArgs a) {
  __shared__ alignas(16) char SM[28672];
  __shared__ int s_cnt;
  int tid = threadIdx.x;
  int bid = blockIdx.x;

  // per-block input-dtype self-detect (deterministic across blocks)
  if (tid == 0) s_cnt = 0;
  __syncthreads();
  {
    int c = 0;
    for (int i = tid; i < 4096; i += 256) {
      unsigned short s = a.x16[2 * i];
      int e = (s >> 7) & 0xFF;
      if (e > 0xC2 || (e != 0 && e < 0x3D)) c++;
    }
    atomicAdd(&s_cnt, c);
  }
  __syncthreads();
  const int isf = (s_cnt > 256) ? 1 : 0;

  // P0: weight transposes (3072) + bias concat (18) + norm1 (2048)
  for (int u = bid; u < 5138; u += 512) {
    if (u < 3072) {
      if (u < 256)       trans_unit(a.wq, a.wqkvT,          512, 512, u, isf, SM);
      else if (u < 512)  trans_unit(a.wk, a.wqkvT + 262144, 512, 512, u - 256, isf, SM);
      else if (u < 768)  trans_unit(a.wv, a.wqkvT + 524288, 512, 512, u - 512, isf, SM);
      else if (u < 1024) trans_unit(a.wo, a.woT,            512, 512, u - 768, isf, SM);
      else if (u < 2048) trans_unit(a.w1, a.w1T,  512, 2048, u - 1024, isf, SM);
      else               trans_unit(a.w2, a.w2T, 2048,  512, u - 2048, isf, SM);
    } else if (u < 3090) {
      int i = (u - 3072) * 256 + tid;
      if (i < 4608) {
        float v;
        if (i < 512) v = rdf(a.bq, i, isf);
        else if (i < 1024) v = rdf(a.bk, i - 512, isf);
        else if (i < 1536) v = rdf(a.bv, i - 1024, isf);
        else if (i < 2048) v = rdf(a.bo, i - 1536, isf);
        else if (i < 4096) v = rdf(a.b1, i - 2048, isf);
        else v = rdf(a.b2, i - 4096, isf);
        a.bcat[i] = v;
      }
    } else {
      norm_unit<0>(a.x16, a.alpha1, a.beta1, a.n1, isf, u - 3090);
    }
  }
  gbar(a.bar, a.gen, 512);
  // P1: fused QKV gemm, 768 tiles (M=8192 N=1536 K=512)
  for (int t = bid; t < 768; t += 512)
    gemm_tile<128, 0, 0, 0>(a.n1, a.wqkvT, a.bcat, nullptr, a.qkb,
                            1536, 512, isf, t & 63, t >> 6, SM);
  gbar(a.bar, a.gen, 512);
  // P2: V transpose, 4096 units
  for (int u = bid; u < 4096; u += 512) vtrans_unit(a.qkb, a.vbt, u, SM);
  gbar(a.bar, a.gen, 512);
  // P3: attention, 1024 tiles (ctx overwrites n1)
  for (int t = bid; t < 1024; t += 512)
    attn_tile(a.qkb, a.vbt, a.mask, a.n1, (t & 31) * 64, t >> 5, SM);
  gbar(a.bar, a.gen, 512);
  // P4: out projection + residual(x) -> x1 f32, 512 tiles
  gemm_tile<64, 1, 1, 0>(a.n1, a.woT, a.bcat + 1536, (const void*)a.x16, a.x1,
                         512, 512, isf, bid & 63, bid >> 6, SM);
  gbar(a.bar, a.gen, 512);
  // P5: norm2 (x1 f32 -> n2 in n1 buffer), 2048 units
  for (int u = bid; u < 2048; u += 512)
    norm_unit<1>(a.x1, a.alpha2, a.beta2, a.n1, isf, u);
  gbar(a.bar, a.gen, 512);
  // P6: ffn1 + relu -> ff1 (qkb overlay), 1024 tiles
  for (int t = bid; t < 1024; t += 512)
    gemm_tile<128, 0, 0, 1>(a.n1, a.w1T, a.bcat + 2048, nullptr, a.qkb,
                            2048, 512, isf, t & 63, t >> 6, SM);
  gbar(a.bar, a.gen, 512);
  // P7: ffn2 + residual(x1) -> d_out, 512 tiles
  gemm_tile<64, 2, 2, 0>(a.qkb, a.w2T, a.bcat + 4096, a.x1, a.d_out,
                         512, 2048, isf, bid & 63, bid >> 6, SM);
}

extern "C" void kernel_launch(void* const* d_in, const int* in_sizes, int n_in,
                              void* d_out, int out_size, void* d_ws, size_t ws_size,
                              hipStream_t stream) {
  char* ws = (char*)d_ws;
  MArgs a;
  a.x16 = (const unsigned short*)d_in[0];
  a.mask = (const int*)d_in[1];
  a.wq = d_in[2];  a.bq = d_in[3];
  a.wk = d_in[4];  a.bk = d_in[5];
  a.wv = d_in[6];  a.bv = d_in[7];
  a.wo = d_in[8];  a.bo = d_in[9];
  a.w1 = d_in[10]; a.b1 = d_in[11];
  a.w2 = d_in[12]; a.b2 = d_in[13];
  a.alpha1 = d_in[14]; a.beta1 = d_in[15];
  a.alpha2 = d_in[16]; a.beta2 = d_in[17];
  a.d_out = d_out;
  a.bar   = (unsigned*)(ws + 0);
  a.gen   = (unsigned*)(ws + 128);
  a.wqkvT = (unsigned short*)(ws + 65536);    // [1536][512]
  a.woT   = (unsigned short*)(ws + 1638400);
  a.w1T   = (unsigned short*)(ws + 2162688);  // [2048][512]
  a.w2T   = (unsigned short*)(ws + 4259840);  // [512][2048]
  a.bcat  = (float*)         (ws + 6356992);
  a.x1    = (float*)         (ws + 6422528);  // [8192][512] f32
  a.n1    = (unsigned short*)(ws + 23199744); // also ctx, n2
  a.qkb   = (unsigned short*)(ws + 31588352); // [8192][1536] (ff1 overlay)
  a.vbt   = (unsigned short*)(ws + 56754176); // [2048][2048]

  // zero the spin-barrier state (graph-capturable async memset)
  hipMemsetAsync(ws, 0, 256, stream);
  mega_k<<<512, 256, 0, stream>>>(a);
}

// Round 10
// 298.795 us; speedup vs baseline: 1.7701x; 1.7701x over previous
//
#include <hip/hip_runtime.h>

typedef __bf16 bfrag __attribute__((ext_vector_type(8)));
typedef float f32x4 __attribute__((ext_vector_type(4)));
typedef unsigned short us8 __attribute__((ext_vector_type(8)));

__device__ __forceinline__ float bf2f(unsigned short s) {
  unsigned u = ((unsigned)s) << 16;
  float f;
  __builtin_memcpy(&f, &u, 4);
  return f;
}
__device__ __forceinline__ unsigned short f2bf(float f) {
  unsigned u;
  __builtin_memcpy(&u, &f, 4);
  u += 0x7fffu + ((u >> 16) & 1u);
  return (unsigned short)(u >> 16);
}
__device__ __forceinline__ float rdf(const void* p, size_t i, int isf) {
  return isf ? ((const float*)p)[i] : bf2f(((const unsigned short*)p)[i]);
}
__device__ __forceinline__ void gld16(const unsigned short* g, unsigned short* l) {
  __builtin_amdgcn_global_load_lds(
      (const __attribute__((address_space(1))) unsigned int*)g,
      (__attribute__((address_space(3))) unsigned int*)l, 16, 0, 0);
}

// -------- layernorm unit: 4 tokens (1/wave) ----------------------------
template <int XMODE>
__device__ void norm_unit(const void* xin, const void* alpha, const void* beta,
                          unsigned short* out, int isf, int u) {
  constexpr int E = 512;
  int xf = XMODE ? 1 : isf;
  int tid = threadIdx.x;
  int wave = tid >> 6, lane = tid & 63;
  size_t tok = (size_t)u * 4 + wave;
  float v[8];
  if (xf) {
    const float* xp = (const float*)xin + tok * E + lane * 8;
    float4 a0 = *(const float4*)xp;
    float4 a1 = *(const float4*)(xp + 4);
    v[0] = a0.x; v[1] = a0.y; v[2] = a0.z; v[3] = a0.w;
    v[4] = a1.x; v[5] = a1.y; v[6] = a1.z; v[7] = a1.w;
  } else {
    us8 uu = *(const us8*)((const unsigned short*)xin + tok * E + lane * 8);
#pragma unroll
    for (int j = 0; j < 8; j++) v[j] = bf2f(uu[j]);
  }
  float s = 0.f, sq = 0.f;
#pragma unroll
  for (int j = 0; j < 8; j++) { s += v[j]; sq += v[j] * v[j]; }
#pragma unroll
  for (int off = 1; off < 64; off <<= 1) {
    s += __shfl_xor(s, off, 64);
    sq += __shfl_xor(sq, off, 64);
  }
  float mean = s * (1.0f / 512.0f);
  float var = fmaxf((sq - 512.0f * mean * mean) * (1.0f / 511.0f), 0.0f);
  float inv = rdf(alpha, 0, isf) / (sqrtf(var) + 1e-6f);
  float be = rdf(beta, 0, isf);
  us8 ov;
#pragma unroll
  for (int j = 0; j < 8; j++) ov[j] = f2bf((v[j] - mean) * inv + be);
  *(us8*)(out + tok * E + lane * 8) = ov;
}

// ---------------- setup: self-detect + weight transposes + bcat + norm1 --
__global__ __launch_bounds__(256) void setup_k(
    const unsigned short* __restrict__ x16,
    const void* wq, const void* wk, const void* wv, const void* wo,
    const void* w1, const void* w2,
    unsigned short* wqkvT, unsigned short* woT,
    unsigned short* w1T, unsigned short* w2T,
    const void* bq, const void* bk, const void* bv, const void* bo,
    const void* b1, const void* b2, float* __restrict__ bcat,
    const void* alpha1, const void* beta1, unsigned short* __restrict__ n1,
    int* __restrict__ flag) {
  __shared__ unsigned short tile[32][33];
  __shared__ int s_cnt;
  int tid = threadIdx.x;
  int bid = blockIdx.x;
  if (tid == 0) s_cnt = 0;
  __syncthreads();
  {
    int c = 0;
    for (int i = tid; i < 4096; i += 256) {
      unsigned short s = x16[2 * i];
      int e = (s >> 7) & 0xFF;
      if (e > 0xC2 || (e != 0 && e < 0x3D)) c++;
    }
    atomicAdd(&s_cnt, c);
  }
  __syncthreads();
  const int isf = (s_cnt > 256) ? 1 : 0;
  if (bid == 0 && tid == 0) flag[0] = isf;

  if (bid >= 3090) {  // norm1
    norm_unit<0>(x16, alpha1, beta1, n1, isf, bid - 3090);
    return;
  }
  if (bid >= 3072) {  // bias concat
    int i = (bid - 3072) * 256 + tid;
    if (i < 4608) {
      float v;
      if (i < 512) v = rdf(bq, i, isf);
      else if (i < 1024) v = rdf(bk, i - 512, isf);
      else if (i < 1536) v = rdf(bv, i - 1024, isf);
      else if (i < 2048) v = rdf(bo, i - 1536, isf);
      else if (i < 4096) v = rdf(b1, i - 2048, isf);
      else v = rdf(b2, i - 4096, isf);
      bcat[i] = v;
    }
    return;
  }
  const void* W;
  unsigned short* Wt;
  int K, N, t;
  if (bid < 1024) {
    K = 512; N = 512; t = bid & 255;
    if (bid < 256) { W = wq; Wt = wqkvT; }
    else if (bid < 512) { W = wk; Wt = wqkvT + 262144; }
    else if (bid < 768) { W = wv; Wt = wqkvT + 524288; }
    else { W = wo; Wt = woT; }
  } else if (bid < 2048) {
    W = w1; Wt = w1T; K = 512; N = 2048; t = bid - 1024;
  } else {
    W = w2; Wt = w2T; K = 2048; N = 512; t = bid - 2048;
  }
  int nx = N >> 5;
  int n0 = (t % nx) * 32, k0 = (t / nx) * 32;
#pragma unroll
  for (int i = 0; i < 4; i++) {
    int e = tid + i * 256;
    int r = e >> 5, c = e & 31;
    tile[r][c] = f2bf(rdf(W, (size_t)(k0 + r) * N + n0 + c, isf));
  }
  __syncthreads();
#pragma unroll
  for (int i = 0; i < 4; i++) {
    int e = tid + i * 256;
    int r = e >> 5, c = e & 31;
    Wt[(size_t)(n0 + r) * K + k0 + c] = tile[c][r];
  }
}

// ---------------- V transpose: qkb v-cols -> vbt[bh][d][s] --------------
__global__ __launch_bounds__(256) void vtrans_k(
    const unsigned short* __restrict__ qkb, unsigned short* __restrict__ vbt) {
  __shared__ unsigned short tile[32][33];
  int tid = threadIdx.x;
  int u = blockIdx.x;
  int s0 = (u & 63) * 32;
  int d0 = ((u >> 6) & 1) * 32;
  int bh = u >> 7, b = bh >> 3, h = bh & 7;
#pragma unroll
  for (int i = 0; i < 4; i++) {
    int e = tid + i * 256;
    int r = e >> 5, c = e & 31;
    tile[r][c] = qkb[((size_t)b * 2048 + s0 + r) * 1536 + 1024 + h * 64 + d0 + c];
  }
  __syncthreads();
#pragma unroll
  for (int i = 0; i < 4; i++) {
    int e = tid + i * 256;
    int r = e >> 5, c = e & 31;
    vbt[((size_t)bh * 64 + d0 + r) * 2048 + s0 + c] = tile[c][r];
  }
}

// ---------------- norm2 standalone (x1 f32 -> n2 bf16) ------------------
__global__ __launch_bounds__(256) void norm2_k(
    const void* __restrict__ xin, const void* __restrict__ alpha,
    const void* __restrict__ beta, unsigned short* __restrict__ out,
    const int* __restrict__ flag) {
  norm_unit<1>(xin, alpha, beta, out, flag[0], blockIdx.x);
}

// ---------------- GEMM: 128xTN tile, BK=64, XOR-swizzled LDS ------------
// LDS slot j of row r holds global k-chunk (j ^ (r&7)); staging lanes read
// the permuted source chunk (same 128B segment -> coalescing intact); frag
// reads at slot (4*ko+quad)^(l16&7) -> 8 lanes per 4-bank group (optimal).
template <int TN, int RES, int OUTM, int RELU>
__global__ __launch_bounds__(256, 3) void gemm2_k(
    const unsigned short* __restrict__ A,
    const unsigned short* __restrict__ Bt,
    const float* __restrict__ bias,
    const void* __restrict__ res,
    void* __restrict__ outp,
    int N, int K, const int* __restrict__ flag) {
  constexpr int MT = (TN == 128) ? 4 : 2;
  constexpr int BROWS = TN / 4;  // Bs rows staged per wave
  __shared__ alignas(16) unsigned short As[128 * 64];  // 16 KB
  __shared__ alignas(16) unsigned short Bs[TN * 64];   // 16/8 KB
  int isf = flag[0];
  int outf32 = (OUTM == 1) || (OUTM == 2 && isf);
  int tid = threadIdx.x;
  int wave = tid >> 6, lane = tid & 63;
  int quad = lane >> 4, l16 = lane & 15, l7 = l16 & 7;
  int wm = (TN == 128) ? (wave >> 1) : wave;
  int wn = (TN == 128) ? (wave & 1) : 0;
  size_t m0 = (size_t)blockIdx.x * 128;
  size_t n0 = (size_t)blockIdx.y * TN;

  int lrow = lane >> 3;                 // 0..7
  int gcol = 8 * ((lane & 7) ^ lrow);   // swizzled source chunk (shorts)

  const unsigned short* ag = A + (m0 + wave * 32 + lrow) * K + gcol;
  const unsigned short* bg = Bt + (n0 + wave * BROWS + lrow) * K + gcol;
  unsigned short* asl = &As[(wave * 32) * 64];
  unsigned short* bsl = &Bs[(wave * BROWS) * 64];

  f32x4 acc[MT][4];
#pragma unroll
  for (int i = 0; i < MT; i++)
#pragma unroll
    for (int j = 0; j < 4; j++) acc[i][j] = {0.f, 0.f, 0.f, 0.f};

  for (int k0 = 0; k0 < K; k0 += 64) {
    __syncthreads();
#pragma unroll
    for (int c = 0; c < 4; c++)
      gld16(ag + (size_t)(8 * c) * K + k0, asl + (8 * c) * 64);
#pragma unroll
    for (int c = 0; c < BROWS / 8; c++)
      gld16(bg + (size_t)(8 * c) * K + k0, bsl + (8 * c) * 64);
    __syncthreads();
#pragma unroll
    for (int ko = 0; ko < 2; ko++) {
      int slot = ((4 * ko + quad) ^ l7) * 8;
      bfrag af[MT], bf[4];
#pragma unroll
      for (int i = 0; i < MT; i++)
        af[i] = *(const bfrag*)&As[(wm * (MT * 16) + i * 16 + l16) * 64 + slot];
#pragma unroll
      for (int j = 0; j < 4; j++)
        bf[j] = *(const bfrag*)&Bs[(wn * 64 + j * 16 + l16) * 64 + slot];
#pragma unroll
      for (int i = 0; i < MT; i++)
#pragma unroll
        for (int j = 0; j < 4; j++)
          acc[i][j] = __builtin_amdgcn_mfma_f32_16x16x32_bf16(af[i], bf[j], acc[i][j], 0, 0, 0);
    }
  }
#pragma unroll
  for (int j = 0; j < 4; j++) {
    size_t n = n0 + wn * 64 + j * 16 + l16;
    float bv = bias[n];
#pragma unroll
    for (int i = 0; i < MT; i++) {
#pragma unroll
      for (int r = 0; r < 4; r++) {
        size_t m = m0 + wm * (MT * 16) + i * 16 + quad * 4 + r;
        float vv = acc[i][j][r] + bv;
        if (RELU) vv = fmaxf(vv, 0.0f);
        if (RES == 1) vv += rdf(res, m * N + n, isf);
        else if (RES == 2) vv += ((const float*)res)[m * N + n];
        if (outf32) ((float*)outp)[m * N + n] = vv;
        else ((unsigned short*)outp)[m * N + n] = f2bf(vv);
      }
    }
  }
}

// ---------------- flash attention (r6-proven body) ----------------------
__global__ __launch_bounds__(256) void attn_k(
    const unsigned short* __restrict__ qkb,  // [8192][1536] q|k|v
    const unsigned short* __restrict__ vbt,  // [32*64][2048] = V^T per bh
    const int* __restrict__ mask,
    unsigned short* __restrict__ ctx) {      // [8192][512]
  constexpr int S = 2048;
  __shared__ alignas(16) unsigned short Kt[64][72];
  __shared__ alignas(16) unsigned short Vt[64][72];  // [d][key]
  __shared__ alignas(16) unsigned short Pl[4][16][68];
  __shared__ float mskf[64];
  int tid = threadIdx.x, wave = tid >> 6, lane = tid & 63;
  int quad = lane >> 4, l16 = lane & 15;
  int q0 = blockIdx.x * 64;
  int bh = blockIdx.y, b = bh >> 3, h = bh & 7;
  size_t rowbase = (size_t)b * S;

  bfrag qf0, qf1;
  {
    const unsigned short* qp =
        qkb + (rowbase + q0 + wave * 16 + l16) * 1536 + h * 64 + quad * 8;
    qf0 = *(const bfrag*)qp;
    qf1 = *(const bfrag*)(qp + 32);
  }
  f32x4 o[4] = {{0, 0, 0, 0}, {0, 0, 0, 0}, {0, 0, 0, 0}, {0, 0, 0, 0}};
  float l_i[4] = {0.f, 0.f, 0.f, 0.f};

  int srow = tid >> 2;
  int c0 = (tid & 3) * 8;
  const unsigned short* kbase = qkb + 512 + h * 64;
  const unsigned short* vrow = vbt + ((size_t)bh * 64 + srow) * S;
  const float SC = 0.18033688f;  // 0.125 * log2(e)

  for (int kt = 0; kt < S; kt += 64) {
    __syncthreads();
    {
      const unsigned short* kp = kbase + (rowbase + kt + srow) * 1536;
      *(uint4*)&Kt[srow][c0]      = *(const uint4*)(kp + c0);
      *(uint4*)&Kt[srow][c0 + 32] = *(const uint4*)(kp + c0 + 32);
      *(uint4*)&Vt[srow][c0]      = *(const uint4*)(vrow + kt + c0);
      *(uint4*)&Vt[srow][c0 + 32] = *(const uint4*)(vrow + kt + c0 + 32);
    }
    if (tid < 64) mskf[tid] = mask[rowbase + kt + tid] ? 0.0f : -1e5f;
    __syncthreads();

    float pr[4][4];
#pragma unroll
    for (int nt = 0; nt < 4; nt++) {
      f32x4 s = {0, 0, 0, 0};
      bfrag k0f = *(const bfrag*)&Kt[nt * 16 + l16][quad * 8];
      bfrag k1f = *(const bfrag*)&Kt[nt * 16 + l16][32 + quad * 8];
      s = __builtin_amdgcn_mfma_f32_16x16x32_bf16(qf0, k0f, s, 0, 0, 0);
      s = __builtin_amdgcn_mfma_f32_16x16x32_bf16(qf1, k1f, s, 0, 0, 0);
      float mb = mskf[nt * 16 + l16];
#pragma unroll
      for (int r = 0; r < 4; r++) {
        float p = __builtin_amdgcn_exp2f(fminf(fmaf(s[r], SC, mb), 50.0f));
        pr[nt][r] = p;
        unsigned u;
        __builtin_memcpy(&u, &p, 4);
        Pl[wave][quad * 4 + r][nt * 16 + l16] = (unsigned short)(u >> 16);
      }
    }
#pragma unroll
    for (int r = 0; r < 4; r++)
      l_i[r] += (pr[0][r] + pr[1][r]) + (pr[2][r] + pr[3][r]);
    // Pl[wave] wave-private; per-wave DS ordering -> no barrier
    bfrag pa0 = *(const bfrag*)&Pl[wave][l16][quad * 8];
    bfrag pa1 = *(const bfrag*)&Pl[wave][l16][32 + quad * 8];
#pragma unroll
    for (int dt = 0; dt < 4; dt++) {
      bfrag v0 = *(const bfrag*)&Vt[dt * 16 + l16][quad * 8];
      bfrag v1 = *(const bfrag*)&Vt[dt * 16 + l16][32 + quad * 8];
      o[dt] = __builtin_amdgcn_mfma_f32_16x16x32_bf16(pa0, v0, o[dt], 0, 0, 0);
      o[dt] = __builtin_amdgcn_mfma_f32_16x16x32_bf16(pa1, v1, o[dt], 0, 0, 0);
    }
  }
#pragma unroll
  for (int r = 0; r < 4; r++) {
#pragma unroll
    for (int off = 1; off < 16; off <<= 1) l_i[r] += __shfl_xor(l_i[r], off, 64);
    l_i[r] = 1.0f / fmaxf(l_i[r], 1e-30f);
  }
#pragma unroll
  for (int dt = 0; dt < 4; dt++) {
#pragma unroll
    for (int r = 0; r < 4; r++) {
      size_t qrow = rowbase + q0 + wave * 16 + quad * 4 + r;
      ctx[qrow * 512 + h * 64 + dt * 16 + l16] = f2bf(o[dt][r] * l_i[r]);
    }
  }
}

extern "C" void kernel_launch(void* const* d_in, const int* in_sizes, int n_in,
                              void* d_out, int out_size, void* d_ws, size_t ws_size,
                              hipStream_t stream) {
  const unsigned short* x = (const unsigned short*)d_in[0];
  const int* mask         = (const int*)d_in[1];
  const void* wq = d_in[2];  const void* bq = d_in[3];
  const void* wk = d_in[4];  const void* bk = d_in[5];
  const void* wv = d_in[6];  const void* bv = d_in[7];
  const void* wo = d_in[8];  const void* bo = d_in[9];
  const void* w1 = d_in[10]; const void* b1 = d_in[11];
  const void* w2 = d_in[12]; const void* b2 = d_in[13];
  const void* alpha1 = d_in[14]; const void* beta1 = d_in[15];
  const void* alpha2 = d_in[16]; const void* beta2 = d_in[17];

  char* ws = (char*)d_ws;
  int* flag            = (int*)(ws + 0);
  unsigned short* wqkvT= (unsigned short*)(ws + 65536);    // [1536][512]
  unsigned short* woT  = (unsigned short*)(ws + 1638400);
  unsigned short* w1T  = (unsigned short*)(ws + 2162688);  // [2048][512]
  unsigned short* w2T  = (unsigned short*)(ws + 4259840);  // [512][2048]
  float*          bcat = (float*)         (ws + 6356992);  // 4608 f32
  float*          x1   = (float*)         (ws + 6422528);  // [8192][512] f32
  unsigned short* n1   = (unsigned short*)(ws + 23199744); // also ctx, n2
  unsigned short* qkb  = (unsigned short*)(ws + 31588352); // [8192][1536]
  unsigned short* vbt  = (unsigned short*)(ws + 56754176); // [2048][2048]
  unsigned short* ff1  = qkb;                              // [8192][2048] overlay

  dim3 blk(256);

  setup_k<<<5138, blk, 0, stream>>>(x, wq, wk, wv, wo, w1, w2,
                                    wqkvT, woT, w1T, w2T,
                                    bq, bk, bv, bo, b1, b2, bcat,
                                    alpha1, beta1, n1, flag);
  // fused QKV: [8192][512] @ [1536][512]^T -> qkb
  gemm2_k<128, 0, 0, 0><<<dim3(64, 12), blk, 0, stream>>>(n1, wqkvT, bcat, nullptr, qkb, 1536, 512, flag);
  vtrans_k<<<4096, blk, 0, stream>>>(qkb, vbt);
  attn_k<<<dim3(32, 32), blk, 0, stream>>>(qkb, vbt, mask, n1);
  // out projection + residual(x) -> x1 f32
  gemm2_k<64, 1, 1, 0><<<dim3(64, 8), blk, 0, stream>>>(n1, woT, bcat + 1536, (const void*)x, x1, 512, 512, flag);
  norm2_k<<<2048, blk, 0, stream>>>(x1, alpha2, beta2, n1, flag);
  // ffn1 + relu -> ff1
  gemm2_k<128, 0, 0, 1><<<dim3(64, 16), blk, 0, stream>>>(n1, w1T, bcat + 2048, nullptr, ff1, 2048, 512, flag);
  // ffn2 + residual(x1) -> d_out
  gemm2_k<64, 2, 2, 0><<<dim3(64, 8), blk, 0, stream>>>(ff1, w2T, bcat + 4096, x1, d_out, 512, 2048, flag);
}